// Round 7
// baseline (2258.381 us; speedup 1.0000x reference)
//
#include <hip/hip_runtime.h>

#define HID   128
#define BATCH 256
#define SEQ   512
#define INSZ  10
#define MB    16                 // batch rows per block (MFMA M)
#define NBLK  (BATCH / MB)       // 16 blocks
#define NTHR  512                // 8 waves
#define HSTR  136                // fp16 row stride for h ping-pong (bank-conflict pad)
#define XSTR  24                 // fp16 row stride for x staging (K padded 10->16, +8 pad)
#define XCH   8                  // x chunk (timesteps per staged chunk)

#define LOG2E  1.4426950408889634f
#define LOG2E2 2.8853900817779268f

typedef _Float16 half8  __attribute__((ext_vector_type(8)));
typedef _Float16 half4  __attribute__((ext_vector_type(4)));
typedef _Float16 half2v __attribute__((ext_vector_type(2)));
typedef float    floatx4 __attribute__((ext_vector_type(4)));

#define MFMA32(A, B, C) __builtin_amdgcn_mfma_f32_16x16x32_f16(A, B, C, 0, 0, 0)
// NOTE: legacy K=16 intrinsic has no underscore before f16 on gfx950
#define MFMA16(A, B, C) __builtin_amdgcn_mfma_f32_16x16x16f16(A, B, C, 0, 0, 0)

// steady-state barrier: LDS-only drain (skip the vmcnt(0) global drain that
// __syncthreads emits every step)
#define BAR_LGKM() asm volatile("s_waitcnt lgkmcnt(0)\n\ts_barrier" ::: "memory")

// rcp + one Newton step: ~0.5 ulp (raw v_rcp compounded to 3.9e-3 in R5)
__device__ __forceinline__ float rcpn(float d)
{
    float r = __builtin_amdgcn_rcpf(d);
    return r * (2.0f - d * r);
}
// inputs pre-scaled by log2e (sig) / 2*log2e (tanh) -> v_exp_f32 used directly
__device__ __forceinline__ float sig_pre(float a)   { return rcpn(1.0f + __builtin_amdgcn_exp2f(-a)); }
__device__ __forceinline__ float tanh_pre(float a)  { return 2.0f * rcpn(1.0f + __builtin_amdgcn_exp2f(-a)) - 1.0f; }
__device__ __forceinline__ float tanh_raw(float x)  { return tanh_pre(x * LOG2E2); }

__device__ __forceinline__ half8 load_wfrag(const float* rowbase, int k0, float scale)
{
    const float4* p = (const float4*)(rowbase + k0);
    float4 a = p[0], b = p[1];
    half8 r;
    r[0] = (_Float16)(a.x * scale); r[1] = (_Float16)(a.y * scale);
    r[2] = (_Float16)(a.z * scale); r[3] = (_Float16)(a.w * scale);
    r[4] = (_Float16)(b.x * scale); r[5] = (_Float16)(b.y * scale);
    r[6] = (_Float16)(b.z * scale); r[7] = (_Float16)(b.w * scale);
    return r;
}

// ===== fused 2-layer LSTM: 513 pipelined steps, one lgkm-barrier per step.
// Step layout: all LDS reads -> all 52 MFMAs -> L0 epilogue -> L1 epilogue.
__global__ __launch_bounds__(NTHR, 2)
void lstm_fused4(const float* __restrict__ x,
                 const float* __restrict__ w_ih0, const float* __restrict__ w_hh0,
                 const float* __restrict__ b_ih0, const float* __restrict__ b_hh0,
                 const float* __restrict__ w_ih1, const float* __restrict__ w_hh1,
                 const float* __restrict__ b_ih1, const float* __restrict__ b_hh1,
                 const float* __restrict__ fc_w,  const float* __restrict__ fc_b,
                 float* __restrict__ out)
{
    const int tid  = threadIdx.x;
    const int lane = tid & 63;
    const int wv   = tid >> 6;        // wave -> hidden cols [16wv, 16wv+16)
    const int m16  = lane & 15;
    const int quad = lane >> 4;
    const int col  = (wv << 4) + m16;
    const int b0   = blockIdx.x * MB;

    __shared__ __align__(16) _Float16 xs[2][XCH * MB * XSTR];  // 12.0 KB
    __shared__ __align__(16) _Float16 hA[2][MB * HSTR];        // 8.5 KB (layer-0 h; also L1 input)
    __shared__ __align__(16) _Float16 hB[2][MB * HSTR];        // 8.5 KB (layer-1 h)

    // gate scales: i,f,o sigmoid -> log2e ; g tanh -> 2*log2e
    const float gsc[4] = {LOG2E, LOG2E, LOG2E2, LOG2E};

    // ---- weight fragments (resident in regs/AGPRs), pre-scaled ----
    half8 Whh0f[4][4], Wih1f[4][4], Whh1f[4][4];
    half4 Wih0f[4];                   // K=16 (padded from 10)
    float bias0[4], bias1[4];
#pragma unroll
    for (int g = 0; g < 4; ++g) {
        const int gr = g * HID + col;
        const float s = gsc[g];
        bias0[g] = (b_ih0[gr] + b_hh0[gr]) * s;
        bias1[g] = (b_ih1[gr] + b_hh1[gr]) * s;
#pragma unroll
        for (int ks = 0; ks < 4; ++ks) {
            Whh0f[g][ks] = load_wfrag(w_hh0 + (size_t)gr * HID, ks * 32 + quad * 8, s);
            Wih1f[g][ks] = load_wfrag(w_ih1 + (size_t)gr * HID, ks * 32 + quad * 8, s);
            Whh1f[g][ks] = load_wfrag(w_hh1 + (size_t)gr * HID, ks * 32 + quad * 8, s);
        }
        half4 r;
#pragma unroll
        for (int j = 0; j < 4; ++j) {
            int k = quad * 4 + j;
            r[j] = (k < INSZ) ? (_Float16)(w_ih0[gr * INSZ + k] * s) : (_Float16)0.0f;
        }
        Wih0f[g] = r;
    }

    // ---- zero LDS (x pads + h ping-pong initial state) ----
    for (int i = tid; i < 2 * XCH * MB * XSTR / 2; i += NTHR) ((int*)&xs[0][0])[i] = 0;
    for (int i = tid; i < 2 * MB * HSTR / 2; i += NTHR) ((int*)&hA[0][0])[i] = 0;
    for (int i = tid; i < 2 * MB * HSTR / 2; i += NTHR) ((int*)&hB[0][0])[i] = 0;

    // ---- stage x chunk 0 ----
    if (tid < 128) {
        const int m = tid >> 3, s = tid & 7;
        const float2* xp = (const float2*)(x + ((size_t)(b0 + m) * SEQ + s) * INSZ);
        _Float16* dst = &xs[0][0] + (s * MB + m) * XSTR;
#pragma unroll
        for (int p = 0; p < 5; ++p) {
            float2 v = xp[p];
            half2v h; h[0] = (_Float16)v.x; h[1] = (_Float16)v.y;
            *(half2v*)(dst + 2 * p) = h;
        }
    }
    __syncthreads();

    const int laneRd = m16 * HSTR + quad * 8;
    const int wrBase = (quad * 4) * HSTR + col;

    float c0[4] = {0.f, 0.f, 0.f, 0.f};
    float c1[4] = {0.f, 0.f, 0.f, 0.f};
    half2v xr[5];                     // packed fp16 x prefetch (threads 0..127)

    for (int t = 0; t <= SEQ; ++t) {
        const int p = t & 1;
        const int sub = t & 7;

        // coalesced x prefetch into regs every 8 steps (2 waves only)
        if (sub == 0 && t + XCH < SEQ && tid < 128) {
            const int m = tid >> 3, s = tid & 7;
            const float2* xp = (const float2*)(x + ((size_t)(b0 + m) * SEQ + (t + XCH + s)) * INSZ);
#pragma unroll
            for (int q = 0; q < 5; ++q) {
                float2 v = xp[q];
                half2v h; h[0] = (_Float16)v.x; h[1] = (_Float16)v.y;
                xr[q] = h;
            }
        }

        // ======== phase 1: ALL LDS fragment reads ========
        const _Float16* haB = &hA[p ^ 1][0] + laneRd;
        half8 ha0 = *(const half8*)(haB);
        half8 ha1 = *(const half8*)(haB + 32);
        half8 ha2 = *(const half8*)(haB + 64);
        half8 ha3 = *(const half8*)(haB + 96);
        const _Float16* hbB = &hB[p][0] + laneRd;
        half8 hb0 = *(const half8*)(hbB);
        half8 hb1 = *(const half8*)(hbB + 32);
        half8 hb2 = *(const half8*)(hbB + 64);
        half8 hb3 = *(const half8*)(hbB + 96);
        half4 xa  = *(const half4*)(&xs[(t >> 3) & 1][0] + (sub * MB + m16) * XSTR + quad * 4);

        // ======== phase 2: ALL MFMAs (L0's 20, then L1's 32) ========
        floatx4 A0 = {bias0[0], bias0[0], bias0[0], bias0[0]};
        floatx4 A1 = {bias0[1], bias0[1], bias0[1], bias0[1]};
        floatx4 A2 = {bias0[2], bias0[2], bias0[2], bias0[2]};
        floatx4 A3 = {bias0[3], bias0[3], bias0[3], bias0[3]};
        floatx4 B0 = {bias1[0], bias1[0], bias1[0], bias1[0]};
        floatx4 B1 = {bias1[1], bias1[1], bias1[1], bias1[1]};
        floatx4 B2 = {bias1[2], bias1[2], bias1[2], bias1[2]};
        floatx4 B3 = {bias1[3], bias1[3], bias1[3], bias1[3]};

        if (t < SEQ) {
            A0 = MFMA16(xa, Wih0f[0], A0); A1 = MFMA16(xa, Wih0f[1], A1);
            A2 = MFMA16(xa, Wih0f[2], A2); A3 = MFMA16(xa, Wih0f[3], A3);
            A0 = MFMA32(ha0, Whh0f[0][0], A0); A1 = MFMA32(ha0, Whh0f[1][0], A1);
            A2 = MFMA32(ha0, Whh0f[2][0], A2); A3 = MFMA32(ha0, Whh0f[3][0], A3);
            A0 = MFMA32(ha1, Whh0f[0][1], A0); A1 = MFMA32(ha1, Whh0f[1][1], A1);
            A2 = MFMA32(ha1, Whh0f[2][1], A2); A3 = MFMA32(ha1, Whh0f[3][1], A3);
            A0 = MFMA32(ha2, Whh0f[0][2], A0); A1 = MFMA32(ha2, Whh0f[1][2], A1);
            A2 = MFMA32(ha2, Whh0f[2][2], A2); A3 = MFMA32(ha2, Whh0f[3][2], A3);
            A0 = MFMA32(ha3, Whh0f[0][3], A0); A1 = MFMA32(ha3, Whh0f[1][3], A1);
            A2 = MFMA32(ha3, Whh0f[2][3], A2); A3 = MFMA32(ha3, Whh0f[3][3], A3);
        }
        if (t > 0) {
            B0 = MFMA32(ha0, Wih1f[0][0], B0); B1 = MFMA32(ha0, Wih1f[1][0], B1);
            B2 = MFMA32(ha0, Wih1f[2][0], B2); B3 = MFMA32(ha0, Wih1f[3][0], B3);
            B0 = MFMA32(ha1, Wih1f[0][1], B0); B1 = MFMA32(ha1, Wih1f[1][1], B1);
            B2 = MFMA32(ha1, Wih1f[2][1], B2); B3 = MFMA32(ha1, Wih1f[3][1], B3);
            B0 = MFMA32(ha2, Wih1f[0][2], B0); B1 = MFMA32(ha2, Wih1f[1][2], B1);
            B2 = MFMA32(ha2, Wih1f[2][2], B2); B3 = MFMA32(ha2, Wih1f[3][2], B3);
            B0 = MFMA32(ha3, Wih1f[0][3], B0); B1 = MFMA32(ha3, Wih1f[1][3], B1);
            B2 = MFMA32(ha3, Wih1f[2][3], B2); B3 = MFMA32(ha3, Wih1f[3][3], B3);
            B0 = MFMA32(hb0, Whh1f[0][0], B0); B1 = MFMA32(hb0, Whh1f[1][0], B1);
            B2 = MFMA32(hb0, Whh1f[2][0], B2); B3 = MFMA32(hb0, Whh1f[3][0], B3);
            B0 = MFMA32(hb1, Whh1f[0][1], B0); B1 = MFMA32(hb1, Whh1f[1][1], B1);
            B2 = MFMA32(hb1, Whh1f[2][1], B2); B3 = MFMA32(hb1, Whh1f[3][1], B3);
            B0 = MFMA32(hb2, Whh1f[0][2], B0); B1 = MFMA32(hb2, Whh1f[1][2], B1);
            B2 = MFMA32(hb2, Whh1f[2][2], B2); B3 = MFMA32(hb2, Whh1f[3][2], B3);
            B0 = MFMA32(hb3, Whh1f[0][3], B0); B1 = MFMA32(hb3, Whh1f[1][3], B1);
            B2 = MFMA32(hb3, Whh1f[2][3], B2); B3 = MFMA32(hb3, Whh1f[3][3], B3);
        }

        // commit prefetched x chunk to the other LDS buffer
        if (sub == 2 && t + 6 < SEQ && tid < 128) {
            const int m = tid >> 3, s = tid & 7;
            _Float16* dst = &xs[((t >> 3) + 1) & 1][0] + (s * MB + m) * XSTR;
#pragma unroll
            for (int q = 0; q < 5; ++q) *(half2v*)(dst + 2 * q) = xr[q];
        }

        // ======== phase 3: epilogues (VALU overlaps matrix-pipe drain) ========
        if (t < SEQ) {
            _Float16* hw = &hA[p][0] + wrBase;
#pragma unroll
            for (int e = 0; e < 4; ++e) {
                float iv = sig_pre(A0[e]);
                float fv = sig_pre(A1[e]);
                float gv = tanh_pre(A2[e]);
                float ov = sig_pre(A3[e]);
                c0[e] = fv * c0[e] + iv * gv;
                hw[e * HSTR] = (_Float16)(ov * tanh_raw(c0[e]));
            }
        }
        if (t > 0) {
            _Float16* hw2 = &hB[p ^ 1][0] + wrBase;
#pragma unroll
            for (int e = 0; e < 4; ++e) {
                float iv = sig_pre(B0[e]);
                float fv = sig_pre(B1[e]);
                float gv = tanh_pre(B2[e]);
                float ov = sig_pre(B3[e]);
                c1[e] = fv * c1[e] + iv * gv;
                hw2[e * HSTR] = (_Float16)(ov * tanh_raw(c1[e]));
            }
        }
        BAR_LGKM();
    }

    // ---- FC epilogue: final h2[511] is in hB[1] ----
    if (tid < 160) {
        const int cls = tid >> 4, b = tid & 15;
        float a = fc_b[cls];
        const float* wr = fc_w + cls * HID;
        const _Float16* hb1 = &hB[1][0] + b * HSTR;
#pragma unroll 8
        for (int k = 0; k < HID; ++k) a += wr[k] * (float)hb1[k];
        out[(size_t)(b0 + b) * 10 + cls] = a;
    }
}

extern "C" void kernel_launch(void* const* d_in, const int* in_sizes, int n_in,
                              void* d_out, int out_size, void* d_ws, size_t ws_size,
                              hipStream_t stream) {
    (void)in_sizes; (void)n_in; (void)out_size; (void)d_ws; (void)ws_size;
    const float* x     = (const float*)d_in[0];
    const float* w_ih0 = (const float*)d_in[1];
    const float* w_hh0 = (const float*)d_in[2];
    const float* b_ih0 = (const float*)d_in[3];
    const float* b_hh0 = (const float*)d_in[4];
    const float* w_ih1 = (const float*)d_in[5];
    const float* w_hh1 = (const float*)d_in[6];
    const float* b_ih1 = (const float*)d_in[7];
    const float* b_hh1 = (const float*)d_in[8];
    const float* fc_w  = (const float*)d_in[9];
    const float* fc_b  = (const float*)d_in[10];
    float* out = (float*)d_out;

    lstm_fused4<<<NBLK, NTHR, 0, stream>>>(x, w_ih0, w_hh0, b_ih0, b_hh0,
                                           w_ih1, w_hh1, b_ih1, b_hh1,
                                           fc_w, fc_b, out);
}